// Round 2
// baseline (412.786 us; speedup 1.0000x reference)
//
#include <hip/hip_runtime.h>
#include <hip/hip_bf16.h>
#include <cstdint>

#define N_NODES  262144
#define N_GRAPHS 1024
#define FEAT     256

using short8 = __attribute__((ext_vector_type(8))) short;
using f32x4  = __attribute__((ext_vector_type(4))) float;

#define MFMA_BF16 __builtin_amdgcn_mfma_f32_16x16x32_bf16

__device__ __forceinline__ unsigned short f2bf(float f){
    unsigned u = __float_as_uint(f);
    u = u + 0x7FFFu + ((u >> 16) & 1u);   // round-to-nearest-even
    return (unsigned short)(u >> 16);
}
__device__ __forceinline__ float sigmoidf_(float x){ return 1.0f/(1.0f+__expf(-x)); }

// ---------------------------------------------------------------------------
// Kernel 1 (prep, fused): blocks [0,704) f32->bf16 converts; [704,961) zero
// num/den; [961,1217) per-graph logit glog[g]=dot(relu(gf[g]),lw[0:256])+lb.
__global__ __launch_bounds__(256) void prep_kernel(
        const float* __restrict__ gf,  const float* __restrict__ pw,
        const float* __restrict__ wih, const float* __restrict__ whh,
        const float* __restrict__ lw,  const float* __restrict__ lb,
        unsigned short* __restrict__ h_bf,  unsigned short* __restrict__ pw_bf,
        unsigned short* __restrict__ wih_bf, unsigned short* __restrict__ whh_bf,
        float* __restrict__ num, float* __restrict__ glog){
    int b = blockIdx.x;
    if (b < 704){                               // converts: 180224 float4
        int i = b*256 + threadIdx.x;
        const float* src; unsigned short* dst; int base;
        if      (i <  65536){ src=gf;  dst=h_bf;   base=i;        }
        else if (i <  81920){ src=pw;  dst=pw_bf;  base=i-65536;  }
        else if (i < 131072){ src=wih; dst=wih_bf; base=i-81920;  }
        else                { src=whh; dst=whh_bf; base=i-131072; }
        float4 v = ((const float4*)src)[base];
        ushort4 o; o.x=f2bf(v.x); o.y=f2bf(v.y); o.z=f2bf(v.z); o.w=f2bf(v.w);
        ((ushort4*)dst)[base] = o;
    } else if (b < 961){                        // zero num+den: 65792 float4
        int i = (b-704)*256 + threadIdx.x;
        float4 z = {0.f,0.f,0.f,0.f};
        ((float4*)num)[i] = z;                  // den is contiguous after num
    } else {                                    // glogit: 1024 waves
        int wid  = (b-961)*4 + (threadIdx.x >> 6);
        int lane = threadIdx.x & 63;
        float4 g = ((const float4*)gf)[wid*64 + lane];
        float4 w = ((const float4*)lw)[lane];
        float p = fmaxf(g.x,0.f)*w.x + fmaxf(g.y,0.f)*w.y +
                  fmaxf(g.z,0.f)*w.z + fmaxf(g.w,0.f)*w.w;
        #pragma unroll
        for (int m=1;m<64;m<<=1) p += __shfl_xor(p, m, 64);
        if (lane==0) glog[wid] = p + lb[0];
    }
}

// ---------------------------------------------------------------------------
// Kernel 2: single pass over node_feats (non-temporal stream).
// wave-per-node: logit dot -> e=exp(leaky(glog+dot)) -> accumulate e*x and e
// per running segment in registers, atomic flush on segment change.
__global__ __launch_bounds__(256) void pass1_kernel(
        const float* __restrict__ nf, const int* __restrict__ seg,
        const float* __restrict__ glog, const float* __restrict__ lw1,
        float* __restrict__ num, float* __restrict__ den){
    const int NPW = 32;                       // nodes per wave (8192 waves)
    int wid  = (blockIdx.x*blockDim.x + threadIdx.x) >> 6;
    int lane = threadIdx.x & 63;
    int n0   = wid * NPW;
    f32x4 w4 = ((const f32x4*)lw1)[lane];     // logit_w[256 + 4*lane ..]
    const f32x4* nf4 = (const f32x4*)nf;

    float a0=0.f,a1=0.f,a2=0.f,a3=0.f,dacc=0.f;
    int   cur = seg[n0];
    float gl  = glog[cur];
    f32x4 x   = __builtin_nontemporal_load(nf4 + (size_t)n0*64 + lane);
    int    s  = cur;

    for (int i=0;i<NPW;i++){
        f32x4 xc = x; int sc = s;
        if (i+1 < NPW){                       // software prefetch next node
            x = __builtin_nontemporal_load(nf4 + (size_t)(n0+i+1)*64 + lane);
            s = seg[n0+i+1];
        }
        if (sc != cur){                       // wave-uniform flush
            atomicAdd(&num[cur*FEAT + lane*4+0], a0);
            atomicAdd(&num[cur*FEAT + lane*4+1], a1);
            atomicAdd(&num[cur*FEAT + lane*4+2], a2);
            atomicAdd(&num[cur*FEAT + lane*4+3], a3);
            if (lane==0) atomicAdd(&den[cur], dacc);
            a0=a1=a2=a3=0.f; dacc=0.f; cur=sc; gl=glog[sc];
        }
        float p = xc[0]*w4[0] + xc[1]*w4[1] + xc[2]*w4[2] + xc[3]*w4[3];
        #pragma unroll
        for (int m=1;m<64;m<<=1) p += __shfl_xor(p, m, 64);
        float q  = gl + p;
        float zf = q > 0.f ? q : 0.01f*q;     // leaky_relu
        float e  = __expf(zf);                // no max-shift needed (zf small)
        a0 += e*xc[0]; a1 += e*xc[1]; a2 += e*xc[2]; a3 += e*xc[3];
        if (lane==0) dacc += e;
    }
    atomicAdd(&num[cur*FEAT + lane*4+0], a0);
    atomicAdd(&num[cur*FEAT + lane*4+1], a1);
    atomicAdd(&num[cur*FEAT + lane*4+2], a2);
    atomicAdd(&num[cur*FEAT + lane*4+3], a3);
    if (lane==0) atomicAdd(&den[cur], dacc);
}

// ---------------------------------------------------------------------------
// Kernel 3 (fused gemm1+gemm2): block = 16 output rows, 4 waves.
// Phase A: x = bf16(elu((num/den)@proj_w^T + pb)) -> LDS [16][264] (padded).
// Phase B: fused GRU gates via 6 MFMA chains, A-frags hoisted to registers.
__global__ __launch_bounds__(256) void gemm_fused_kernel(
        const float* __restrict__ num, const float* __restrict__ den,
        const unsigned short* __restrict__ pw_bf, const float* __restrict__ pb,
        const unsigned short* __restrict__ h_bf,
        const unsigned short* __restrict__ wih_bf, const unsigned short* __restrict__ whh_bf,
        const float* __restrict__ bih, const float* __restrict__ bhh,
        const float* __restrict__ gf, float* __restrict__ out){
    __shared__ unsigned short x_s[16][264];   // +8 shorts pad: 2-way-free reads
    int r0   = blockIdx.x * 16;               // 64 blocks
    int wave = threadIdx.x >> 6;
    int lane = threadIdx.x & 63;
    int rq   = lane & 15;
    int kgrp = (lane >> 4) * 8;
    int arow = r0 + rq;

    // hoisted A-fragments for phase A (num/den rows, bf16-converted once)
    float dv  = den[arow];
    float inv = dv > 0.f ? 1.0f/dv : 0.f;
    short8 af[8];
    #pragma unroll
    for (int t=0;t<8;t++){
        int kb = t*32 + kgrp;
        float4 u0 = *(const float4*)(num + arow*FEAT + kb);
        float4 u1 = *(const float4*)(num + arow*FEAT + kb + 4);
        af[t][0]=(short)f2bf(u0.x*inv); af[t][1]=(short)f2bf(u0.y*inv);
        af[t][2]=(short)f2bf(u0.z*inv); af[t][3]=(short)f2bf(u0.w*inv);
        af[t][4]=(short)f2bf(u1.x*inv); af[t][5]=(short)f2bf(u1.y*inv);
        af[t][6]=(short)f2bf(u1.z*inv); af[t][7]=(short)f2bf(u1.w*inv);
    }
    #pragma unroll
    for (int j=0;j<4;j++){                    // 4 col-tiles per wave
        int ct = wave*4 + j;
        int brow = ct*16 + rq;
        f32x4 acc = {0.f,0.f,0.f,0.f};
        #pragma unroll
        for (int t=0;t<8;t++){
            short8 bfr = *(const short8*)(pw_bf + brow*FEAT + t*32 + kgrp);
            acc = MFMA_BF16(af[t], bfr, acc, 0, 0, 0);
        }
        #pragma unroll
        for (int r=0;r<4;r++){
            int rl  = (lane>>4)*4 + r;        // C/D: col=lane&15, row=(lane>>4)*4+r
            int col = ct*16 + rq;
            float g  = acc[r] + pb[col];
            float xv = g > 0.f ? g : (__expf(g) - 1.0f);   // elu
            x_s[rl][col] = f2bf(xv);
        }
    }
    __syncthreads();

    // phase B: hoist x (LDS) and h (L2) A-fragments
    short8 ax[8], ah[8];
    #pragma unroll
    for (int t=0;t<8;t++){
        int kb = t*32 + kgrp;
        ax[t] = *(const short8*)&x_s[rq][kb];
        ah[t] = *(const short8*)(h_bf + arow*FEAT + kb);
    }
    #pragma unroll
    for (int j=0;j<4;j++){
        int ct = wave*4 + j;
        int wrow = ct*16 + rq;
        f32x4 ir={0,0,0,0}, iz={0,0,0,0}, inn={0,0,0,0};
        f32x4 hr={0,0,0,0}, hz={0,0,0,0}, hnn={0,0,0,0};
        #pragma unroll
        for (int t=0;t<8;t++){
            int kb = t*32 + kgrp;
            short8 bir = *(const short8*)(wih_bf + (wrow      )*FEAT + kb);
            short8 biz = *(const short8*)(wih_bf + (wrow + 256)*FEAT + kb);
            short8 bin = *(const short8*)(wih_bf + (wrow + 512)*FEAT + kb);
            short8 bhr = *(const short8*)(whh_bf + (wrow      )*FEAT + kb);
            short8 bhz = *(const short8*)(whh_bf + (wrow + 256)*FEAT + kb);
            short8 bhn = *(const short8*)(whh_bf + (wrow + 512)*FEAT + kb);
            ir  = MFMA_BF16(ax[t], bir, ir , 0,0,0);
            iz  = MFMA_BF16(ax[t], biz, iz , 0,0,0);
            inn = MFMA_BF16(ax[t], bin, inn, 0,0,0);
            hr  = MFMA_BF16(ah[t], bhr, hr , 0,0,0);
            hz  = MFMA_BF16(ah[t], bhz, hz , 0,0,0);
            hnn = MFMA_BF16(ah[t], bhn, hnn, 0,0,0);
        }
        #pragma unroll
        for (int r=0;r<4;r++){
            int row = r0 + (lane>>4)*4 + r;
            int col = ct*16 + rq;
            float vir = ir [r] + bih[col      ];
            float viz = iz [r] + bih[col + 256];
            float vin = inn[r] + bih[col + 512];
            float vhr = hr [r] + bhh[col      ];
            float vhz = hz [r] + bhh[col + 256];
            float vhn = hnn[r] + bhh[col + 512];
            float rg = sigmoidf_(vir + vhr);
            float zg = sigmoidf_(viz + vhz);
            float ng = tanhf(vin + rg*vhn);
            float h  = gf[row*FEAT + col];
            out[row*FEAT + col] = (1.f - zg)*ng + zg*h;
        }
    }
}

// ---------------------------------------------------------------------------
extern "C" void kernel_launch(void* const* d_in, const int* in_sizes, int n_in,
                              void* d_out, int out_size, void* d_ws, size_t ws_size,
                              hipStream_t stream){
    const float* nf  = (const float*)d_in[0];
    const float* gf  = (const float*)d_in[1];
    const int*   seg = (const int*)  d_in[2];
    const float* lw  = (const float*)d_in[4];   // (1, 512)
    const float* lb  = (const float*)d_in[5];
    const float* pw  = (const float*)d_in[6];   // (256,256)
    const float* pb  = (const float*)d_in[7];
    const float* wih = (const float*)d_in[8];   // (768,256)
    const float* whh = (const float*)d_in[9];
    const float* bih = (const float*)d_in[10];
    const float* bhh = (const float*)d_in[11];
    float* out = (float*)d_out;

    // workspace layout (~3 MB total); num and den MUST stay contiguous (zeroing)
    float* num  = (float*)d_ws;                 // 1024*256
    float* den  = num + N_GRAPHS*FEAT;          // 1024
    float* glog = den + N_GRAPHS;               // 1024
    unsigned short* h_bf   = (unsigned short*)(glog + N_GRAPHS);
    unsigned short* pw_bf  = h_bf   + N_GRAPHS*FEAT;
    unsigned short* wih_bf = pw_bf  + FEAT*FEAT;
    unsigned short* whh_bf = wih_bf + 3*FEAT*FEAT;

    prep_kernel      <<<1217, 256, 0, stream>>>(gf, pw, wih, whh, lw, lb,
                                                h_bf, pw_bf, wih_bf, whh_bf, num, glog);
    pass1_kernel     <<<2048, 256, 0, stream>>>(nf, seg, glog, lw + FEAT, num, den);
    gemm_fused_kernel<<<64,   256, 0, stream>>>(num, den, pw_bf, pb, h_bf,
                                                wih_bf, whh_bf, bih, bhh, gf, out);
}